// Round 6
// baseline (272.559 us; speedup 1.0000x reference)
//
#include <hip/hip_runtime.h>

// LengthRegulator: expand x (B,T,H) by per-token durations into (B,MAXLEN,H),
// plus sinusoidal positional rows per within-token offset, plus mel lengths.
// B=64, T=160, H=256, MAXLEN=2000 (fixed by the harness's setup_inputs).
//
// v4: persistent-grid expand. Evidence so far: v0 (fused+search) ~= v3
// (split+branchless) ~= 267-271 us total, i.e. our kernel ~107 us for 274 MB
// (2.6 TB/s) while the harness's own fill sustains 6.5 TB/s. The shared trait
// of all prior variants was 8000 single-shot micro-blocks (128 B of stores
// per thread, one load->store chain, exit) -> block churn + unhidden latency.
// v4 launches 2048 blocks (8/CU, one residency generation) that LOOP over
// frame-tiles: loop-level pipelining hides gather latency behind stores of
// the previous tile. Each wave handles 4 contiguous frames: 1 int4 map
// broadcast + 4 KB contiguous stores per stream.
constexpr int B      = 64;
constexpr int T      = 160;
constexpr int H      = 256;
constexpr int MAXLEN = 2000;
constexpr int FPB    = 16;   // frames per tile (4 waves x 4 contiguous frames)
constexpr int NTH    = 256;
constexpr int TPB_X  = 32;   // persistent x-blocks per batch (32*64 = 2048 blocks)

// ---------------- Kernel A: per-batch scan + map build (64 blocks) ----------
// map[b*MAXLEN + f] = (token << 8) | pos_within   for valid frames (pw in 0..11)
//                   = -1                          for the invalid tail
__global__ __launch_bounds__(NTH) void build_map_kernel(
    const int* __restrict__ duration,
    int*       __restrict__ map,
    float*     __restrict__ out)      // only for the mel_len chunk
{
    __shared__ int s_scan[NTH];
    const int b   = blockIdx.x;
    const int tid = threadIdx.x;

    int d = (tid < T) ? duration[b * T + tid] : 0;
    s_scan[tid] = d;
    __syncthreads();
    #pragma unroll
    for (int off = 1; off < NTH; off <<= 1) {
        int v   = s_scan[tid];
        int add = (tid >= off) ? s_scan[tid - off] : 0;
        __syncthreads();
        s_scan[tid] = v + add;
        __syncthreads();
    }
    const int csum    = s_scan[tid];        // inclusive prefix (valid for tid < T)
    const int excl    = csum - d;           // exclusive prefix
    const int mel_len = s_scan[T - 1];

    if (tid == 0)
        out[(size_t)2 * B * MAXLEN * H + b] = (float)mel_len;

    int* bm = map + b * MAXLEN;

    // invalid tail
    for (int f = mel_len + tid; f < MAXLEN; f += NTH)
        bm[f] = -1;

    // scatter: token tid owns frames [excl, csum). duration < 12 so pw fits 8 bits.
    if (tid < T) {
        for (int f = excl; f < csum; ++f)
            bm[f] = (tid << 8) | (f - excl);
    }
}

// ---------------- Kernel B: persistent streaming expand (32 x 64 blocks) ----
__global__ __launch_bounds__(NTH) void expand_kernel(
    const float* __restrict__ x,
    const float* __restrict__ pos_enc,
    const int*   __restrict__ map,
    float*       __restrict__ out)
{
    const int tid  = threadIdx.x;
    const int b    = blockIdx.y;
    const int wave = tid >> 6;   // 0..3
    const int lane = tid & 63;   // float4 index within the 256-wide row

    const float* xb   = x   + (size_t)b * T * H;
    float*       outb = out + (size_t)b * MAXLEN * H;
    float*       posb = outb + (size_t)B * MAXLEN * H;
    const int*   bm   = map + b * MAXLEN;

    constexpr int NTILE = MAXLEN / FPB;   // 125 tiles per batch
    for (int tx = blockIdx.x; tx < NTILE; tx += TPB_X) {
        const int fw = tx * FPB + 4 * wave;        // 4 contiguous frames/wave
        const int4 m4 = *(const int4*)(bm + fw);   // wave-uniform 16B broadcast
        const int mm[4] = { m4.x, m4.y, m4.z, m4.w };

        // all 8 row loads in flight before any store (invalid -> token 0 /
        // pw 0, a broadcast L2 hit; zeroed by the scale below)
        float4 xo[4], po[4];
        #pragma unroll
        for (int j = 0; j < 4; ++j) {
            const int msel = (mm[j] < 0) ? 0 : mm[j];
            const int t  = msel >> 8;
            const int pw = msel & 255;
            xo[j] = ((const float4*)(xb      + (size_t)t  * H))[lane];
            po[j] = ((const float4*)(pos_enc + (size_t)pw * H))[lane];
        }
        #pragma unroll
        for (int j = 0; j < 4; ++j) {
            const float s = (mm[j] >= 0) ? 1.0f : 0.0f;
            const int   f = fw + j;
            float4 a = make_float4(xo[j].x * s, xo[j].y * s, xo[j].z * s, xo[j].w * s);
            float4 p = make_float4(po[j].x * s, po[j].y * s, po[j].z * s, po[j].w * s);
            ((float4*)(outb + (size_t)f * H))[lane] = a;
            ((float4*)(posb + (size_t)f * H))[lane] = p;
        }
    }
}

// ---------------- Fallback: original fused kernel (if ws too small) ---------
__global__ __launch_bounds__(NTH) void lr_kernel(
    const float* __restrict__ x,
    const float* __restrict__ pos_enc,
    const int*   __restrict__ duration,
    float*       __restrict__ out)
{
    __shared__ int s_scan[NTH];
    __shared__ int s_csum[T];
    __shared__ int s_excl[T];

    const int b   = blockIdx.y;
    const int tid = threadIdx.x;

    int d = (tid < T) ? duration[b * T + tid] : 0;
    s_scan[tid] = d;
    __syncthreads();
    #pragma unroll
    for (int off = 1; off < NTH; off <<= 1) {
        int v   = s_scan[tid];
        int add = (tid >= off) ? s_scan[tid - off] : 0;
        __syncthreads();
        s_scan[tid] = v + add;
        __syncthreads();
    }
    if (tid < T) {
        s_csum[tid] = s_scan[tid];
        s_excl[tid] = s_scan[tid] - d;
    }
    __syncthreads();

    const int mel_len = s_csum[T - 1];
    if (blockIdx.x == 0 && tid == 0) {
        out[(size_t)2 * B * MAXLEN * H + b] = (float)mel_len;
    }

    const int wave = tid >> 6;
    const int lane = tid & 63;
    const size_t out_base = (size_t)b * MAXLEN * H;
    const size_t pos_base = (size_t)B * MAXLEN * H + out_base;
    const int f0 = blockIdx.x * FPB;

    for (int i = wave; i < FPB; i += 4) {
        const int f = f0 + i;
        if (f >= MAXLEN) break;
        const bool valid = (f < mel_len);

        int lo = 0, hi = T;
        while (lo < hi) {
            int mid = (lo + hi) >> 1;
            if (s_csum[mid] <= f) lo = mid + 1; else hi = mid;
        }
        const int idx = min(lo, T - 1);

        float4 xo = make_float4(0.f, 0.f, 0.f, 0.f);
        float4 po = xo;
        if (valid) {
            const int pw = f - s_excl[idx];
            xo = ((const float4*)(x + ((size_t)b * T + idx) * H))[lane];
            po = ((const float4*)(pos_enc + (size_t)pw * H))[lane];
        }
        ((float4*)(out + out_base + (size_t)f * H))[lane] = xo;
        ((float4*)(out + pos_base + (size_t)f * H))[lane] = po;
    }
}

extern "C" void kernel_launch(void* const* d_in, const int* in_sizes, int n_in,
                              void* d_out, int out_size, void* d_ws, size_t ws_size,
                              hipStream_t stream)
{
    const float* x        = (const float*)d_in[0];
    const float* pos_enc  = (const float*)d_in[1];
    const int*   duration = (const int*)d_in[2];
    float*       out      = (float*)d_out;

    const size_t map_bytes = (size_t)B * MAXLEN * sizeof(int);
    if (d_ws != nullptr && ws_size >= map_bytes) {
        int* map = (int*)d_ws;
        build_map_kernel<<<dim3(B), NTH, 0, stream>>>(duration, map, out);
        expand_kernel<<<dim3(TPB_X, B), NTH, 0, stream>>>(x, pos_enc, map, out);
    } else {
        dim3 grid((MAXLEN + FPB - 1) / FPB, B);
        lr_kernel<<<grid, NTH, 0, stream>>>(x, pos_enc, duration, out);
    }
}